// Round 2
// baseline (1360.552 us; speedup 1.0000x reference)
//
#include <hip/hip_runtime.h>

#define B_ 32
#define P_ 4096
#define Q_ 64
#define D_ 128

// workspace layout (floats)
#define T_SIZE (B_*Q_*D_)       // 262144 floats
#define PART_STRIDE 772         // [L, S, v:128, mxH:128, mnH:128, mxC:128, mxHC:128, mxM:128]

// ---------------------------------------------------------------------------
// k_T: T[b,q,d] = sum_e W[d,e] * U[b,q,e]
// grid 256 = 32 b * 8 q-chunks, 256 threads
// ---------------------------------------------------------------------------
__global__ __launch_bounds__(256) void k_T(const float* __restrict__ U,
                                           const float* __restrict__ W,
                                           float* __restrict__ T) {
  __shared__ float Wl[128*132];
  __shared__ float Ul[8*128];
  const int b = blockIdx.x >> 3, qc = blockIdx.x & 7;
  const int t = threadIdx.x;
#pragma unroll
  for (int k = 0; k < 16; ++k) {
    int i = t*4 + k*1024;                 // 16384 floats of W
    float4 wv = *(const float4*)(W + i);
    int d = i >> 7, e = i & 127;
    *(float4*)(&Wl[d*132 + e]) = wv;
  }
  {
    int i = t*4;                          // 1024 floats of U slice
    int q = i >> 7, e = i & 127;
    *(float4*)(&Ul[q*128 + e]) =
        *(const float4*)(U + ((size_t)(b*Q_ + qc*8 + q))*D_ + e);
  }
  __syncthreads();
  const int d = t & 127, qhalf = t >> 7;
#pragma unroll
  for (int pass = 0; pass < 4; ++pass) {
    const int q = pass*2 + qhalf;
    float acc = 0.f;
#pragma unroll
    for (int e = 0; e < 128; e += 4) {
      float4 wv = *(float4*)(&Wl[d*132 + e]);
      float4 uv = *(float4*)(&Ul[q*128 + e]);
      acc += wv.x*uv.x + wv.y*uv.y + wv.z*uv.z + wv.w*uv.w;
    }
    T[((size_t)(b*Q_ + qc*8 + q))*D_ + d] = acc;
  }
}

// ---------------------------------------------------------------------------
// k_main: per (b, 512-row chunk): scores, softmax, c2q, online q2c, masked maxes
// grid 256 = 32 b * 8 chunks, 512 threads (8 waves, 64 rows/wave, groups of 8)
// H rows are read via wave-uniform (readfirstlane) pointers -> scalar/SMEM path,
// no LDS staging for H, no long-lived M/tok register arrays -> no spills.
// ---------------------------------------------------------------------------
__global__ __launch_bounds__(512, 1) void k_main(
    const float* __restrict__ H, const float* __restrict__ U,
    const float* __restrict__ M, const int* __restrict__ tok,
    const float* __restrict__ T, float* __restrict__ part) {
  __shared__ float Tl[Q_*132];      // 33792 B, padded stride (lane=q reads rows)
  __shared__ float Ut[D_*68];       // 34816 B, U transposed [d][q], padded
  __shared__ float wl[8][512];      // 16384 B, per-wave softmax weights
  __shared__ float comb[8*772];     // reuse region for cross-wave combine? NO -- separate below
  // (comb declared but aliased onto wl region is risky; keep its own 24.7KB)
  const int bid = blockIdx.x;
  const int b = bid >> 3, chunk = bid & 7;
  const int t = threadIdx.x, wv = t >> 6, l = t & 63;
  const float* Tb = T + (size_t)b*Q_*D_;
  const float* Ub = U + (size_t)b*Q_*D_;
#pragma unroll
  for (int k = 0; k < 4; ++k) {
    int i = t*4 + k*2048;                 // 8192 floats each of T and U
    int q = i >> 7, d = i & 127;
    float4 tv = *(const float4*)(Tb + i);
    *(float4*)(&Tl[q*132 + d]) = tv;
    float4 uv = *(const float4*)(Ub + i);
    Ut[(d+0)*68 + q] = uv.x;
    Ut[(d+1)*68 + q] = uv.y;
    Ut[(d+2)*68 + q] = uv.z;
    Ut[(d+3)*68 + q] = uv.w;
  }
  __syncthreads();

  const float* Hb = H + (size_t)b*P_*D_;
  const float* Mb = M + (size_t)b*P_*D_;
  const int*  tkb = tok + b*P_;
  float* wlW = wl[wv];

  float Lmax = -3.0e38f, ssum = 0.f, v0 = 0.f, v1 = 0.f;
  float mxH0 = -3.0e38f, mxH1 = -3.0e38f, mnH0 = 3.0e38f, mnH1 = 3.0e38f;
  float mxC0 = -3.0e38f, mxC1 = -3.0e38f, mxHC0 = -3.0e38f, mxHC1 = -3.0e38f;
  float mxM0 = -3.0e38f, mxM1 = -3.0e38f;

  const int rowW = chunk*512 + wv*64;
#pragma unroll 1
  for (int g = 0; g < 8; ++g) {
    const int row0 = rowW + g*8;
    // wave-uniform row pointers (scalar loads in the score loop)
    const float* hrs[8];
#pragma unroll
    for (int r = 0; r < 8; ++r) {
      int ru = __builtin_amdgcn_readfirstlane(row0 + r);
      hrs[r] = Hb + (size_t)ru*D_;
    }
    // per-lane H values (needed for q2c accumulation and pool maxes)
    float h0[8], h1[8];
#pragma unroll
    for (int r = 0; r < 8; ++r) {
      h0[r] = hrs[r][l];
      h1[r] = hrs[r][l + 64];
    }
    // ---- scores: lane = q, s[r] = H[row r] . T[q] ----
    float s[8] = {0,0,0,0,0,0,0,0};
#pragma unroll
    for (int d0 = 0; d0 < 128; d0 += 4) {
      float4 tq = *(float4*)(&Tl[l*132 + d0]);
#pragma unroll
      for (int r = 0; r < 8; ++r) {
        float4 hv = *(const float4*)(hrs[r] + d0);   // uniform -> s_load
        s[r] += tq.x*hv.x + tq.y*hv.y + tq.z*hv.z + tq.w*hv.w;
      }
    }
    // ---- softmax over q (cross-lane), weights to LDS, online q2c ----
#pragma unroll
    for (int r = 0; r < 8; ++r) {
      float m = s[r];
#pragma unroll
      for (int off = 32; off; off >>= 1) m = fmaxf(m, __shfl_xor(m, off));
      float e = __expf(s[r] - m);
      float sum = e;
#pragma unroll
      for (int off = 32; off; off >>= 1) sum += __shfl_xor(sum, off);
      wlW[r*64 + l] = e / sum;
      // online softmax over row-maxes -> q2c accumulation
      float nm = fmaxf(Lmax, m);
      float so = __expf(Lmax - nm);
      float pr = __expf(m - nm);
      v0 = v0*so + pr*h0[r];
      v1 = v1*so + pr*h1[r];
      ssum = ssum*so + pr;
      Lmax = nm;
    }
    // ---- c2q: lane owns d = {l, l+64}; U transposed so reads are b128 over q ----
    float c0[8] = {0,0,0,0,0,0,0,0}, c1[8] = {0,0,0,0,0,0,0,0};
#pragma unroll
    for (int q0 = 0; q0 < 64; q0 += 4) {
      float4 ua = *(float4*)(&Ut[l*68 + q0]);
      float4 ub = *(float4*)(&Ut[(l + 64)*68 + q0]);
#pragma unroll
      for (int r = 0; r < 8; ++r) {
        float4 ww = *(float4*)(&wlW[r*64 + q0]);
        c0[r] += ww.x*ua.x + ww.y*ua.y + ww.z*ua.z + ww.w*ua.w;
        c1[r] += ww.x*ub.x + ww.y*ub.y + ww.z*ub.z + ww.w*ub.w;
      }
    }
    // ---- masked pool maxes (token==PAD excluded); M/tok loaded here, short-lived ----
    float m0[8], m1[8];
#pragma unroll
    for (int r = 0; r < 8; ++r) {
      const float* mp = Mb + (size_t)(row0 + r)*D_;
      m0[r] = mp[l];
      m1[r] = mp[l + 64];
    }
#pragma unroll
    for (int r = 0; r < 8; ++r) {
      int tk = tkb[row0 + r];
      if (tk != 0) {
        mxH0  = fmaxf(mxH0,  h0[r]);        mxH1  = fmaxf(mxH1,  h1[r]);
        mnH0  = fminf(mnH0,  h0[r]);        mnH1  = fminf(mnH1,  h1[r]);
        mxC0  = fmaxf(mxC0,  c0[r]);        mxC1  = fmaxf(mxC1,  c1[r]);
        mxHC0 = fmaxf(mxHC0, h0[r]*c0[r]);  mxHC1 = fmaxf(mxHC1, h1[r]*c1[r]);
        mxM0  = fmaxf(mxM0,  m0[r]);        mxM1  = fmaxf(mxM1,  m1[r]);
      }
    }
  }
  __syncthreads();
  // per-wave partials into comb scratch (772 floats/wave)
  float* sc = comb + wv*772;
  if (l == 0) { sc[0] = Lmax; sc[1] = ssum; }
  sc[2 + l]   = v0;     sc[2 + l + 64]   = v1;
  sc[130 + l] = mxH0;   sc[130 + l + 64] = mxH1;
  sc[258 + l] = mnH0;   sc[258 + l + 64] = mnH1;
  sc[386 + l] = mxC0;   sc[386 + l + 64] = mxC1;
  sc[514 + l] = mxHC0;  sc[514 + l + 64] = mxHC1;
  sc[642 + l] = mxM0;   sc[642 + l + 64] = mxM1;
  __syncthreads();
  if (t < 128) {
    float L = -3.0e38f;
#pragma unroll
    for (int w = 0; w < 8; ++w) L = fmaxf(L, comb[w*772]);
    float S = 0.f, V = 0.f;
    float mh = -3.0e38f, nh = 3.0e38f, mc = -3.0e38f, mhc = -3.0e38f, mm = -3.0e38f;
#pragma unroll
    for (int w = 0; w < 8; ++w) {
      const float* s0 = comb + w*772;
      float e = __expf(s0[0] - L);
      S += s0[1]*e;
      V += s0[2 + t]*e;
      mh  = fmaxf(mh,  s0[130 + t]);
      nh  = fminf(nh,  s0[258 + t]);
      mc  = fmaxf(mc,  s0[386 + t]);
      mhc = fmaxf(mhc, s0[514 + t]);
      mm  = fmaxf(mm,  s0[642 + t]);
    }
    float* pp = part + (size_t)bid*PART_STRIDE;
    if (t == 0) { pp[0] = L; pp[1] = S; }
    pp[2 + t]   = V;
    pp[130 + t] = mh;
    pp[258 + t] = nh;
    pp[386 + t] = mc;
    pp[514 + t] = mhc;
    pp[642 + t] = mm;
  }
}

// ---------------------------------------------------------------------------
// k_final: merge 8 chunk-partials per batch, build pooled[640], classifier
// grid 32 (one per batch), 128 threads (t = d)
// ---------------------------------------------------------------------------
__global__ __launch_bounds__(128) void k_final(const float* __restrict__ part,
                                               const float* __restrict__ Wc,
                                               float* __restrict__ out) {
  __shared__ float pooled[640];
  __shared__ float r0s[2], r1s[2];
  const int b = blockIdx.x, t = threadIdx.x;
  const float* pb = part + (size_t)b*8*PART_STRIDE;
  float L = -3.0e38f;
#pragma unroll
  for (int c = 0; c < 8; ++c) L = fmaxf(L, pb[c*PART_STRIDE]);
  float S = 0.f, V = 0.f;
  float mh = -3.0e38f, nh = 3.0e38f, mc = -3.0e38f, mhc = -3.0e38f, mm = -3.0e38f;
#pragma unroll
  for (int c = 0; c < 8; ++c) {
    const float* p = pb + c*PART_STRIDE;
    float e = __expf(p[0] - L);
    S += p[1]*e;
    V += p[2 + t]*e;
    mh  = fmaxf(mh,  p[130 + t]);
    nh  = fminf(nh,  p[258 + t]);
    mc  = fmaxf(mc,  p[386 + t]);
    mhc = fmaxf(mhc, p[514 + t]);
    mm  = fmaxf(mm,  p[642 + t]);
  }
  float q2c = V / S;
  pooled[t]       = mh;                               // H section
  pooled[128 + t] = mc;                               // c2q section
  pooled[256 + t] = mhc;                              // H*c2q section
  pooled[384 + t] = (q2c >= 0.f) ? q2c*mh : q2c*nh;   // H*q2c section
  pooled[512 + t] = mm;                               // M section
  __syncthreads();
  float a0 = 0.f, a1 = 0.f;
#pragma unroll
  for (int k = t; k < 640; k += 128) {
    float pv = pooled[k];
    a0 += pv*Wc[k*2 + 0];
    a1 += pv*Wc[k*2 + 1];
  }
#pragma unroll
  for (int off = 32; off; off >>= 1) {
    a0 += __shfl_xor(a0, off);
    a1 += __shfl_xor(a1, off);
  }
  if ((t & 63) == 0) { r0s[t >> 6] = a0; r1s[t >> 6] = a1; }
  __syncthreads();
  if (t == 0) {
    out[b*2 + 0] = r0s[0] + r0s[1];
    out[b*2 + 1] = r1s[0] + r1s[1];
  }
}

// ---------------------------------------------------------------------------
extern "C" void kernel_launch(void* const* d_in, const int* in_sizes, int n_in,
                              void* d_out, int out_size, void* d_ws, size_t ws_size,
                              hipStream_t stream) {
  const float* H   = (const float*)d_in[0];
  const float* U   = (const float*)d_in[1];
  const float* M   = (const float*)d_in[2];
  const int*   tok = (const int*)d_in[3];
  const float* Wa  = (const float*)d_in[4];
  const float* Wc  = (const float*)d_in[5];
  float* out = (float*)d_out;
  float* wsf = (float*)d_ws;
  float* T    = wsf;
  float* part = wsf + T_SIZE;

  hipLaunchKernelGGL(k_T,     dim3(256), dim3(256), 0, stream, U, Wa, T);
  hipLaunchKernelGGL(k_main,  dim3(256), dim3(512), 0, stream, H, U, M, tok, T, part);
  hipLaunchKernelGGL(k_final, dim3(32),  dim3(128), 0, stream, part, Wc, out);
}

// Round 3
// 105.795 us; speedup vs baseline: 12.8603x; 12.8603x over previous
//
#include <hip/hip_runtime.h>

#define B_ 32
#define P_ 4096
#define Q_ 64
#define D_ 128

#define T_SIZE (B_*Q_*D_)       // 262144 floats (fp32 T workspace)
#define PART_STRIDE 772         // [L, S, v:128, mxH:128, mnH:128, mxC:128, mxHC:128, mxM:128]
#define NCHUNK 16
#define CHUNK_ROWS 256

typedef __attribute__((ext_vector_type(8))) short bf16x8;
typedef __attribute__((ext_vector_type(4))) float f32x4;

__device__ __forceinline__ unsigned int asu(float x) { return __float_as_uint(x); }
__device__ __forceinline__ float asf(unsigned int x) { return __uint_as_float(x); }

// ---------------------------------------------------------------------------
// k_T: T[b,q,d] = sum_e W[d,e] * U[b,q,e]   (fp32, verified in rounds 1-2)
// grid 256 = 32 b * 8 q-chunks, 256 threads
// ---------------------------------------------------------------------------
__global__ __launch_bounds__(256) void k_T(const float* __restrict__ U,
                                           const float* __restrict__ W,
                                           float* __restrict__ T) {
  __shared__ float Wl[128*132];
  __shared__ float Ul[8*128];
  const int b = blockIdx.x >> 3, qc = blockIdx.x & 7;
  const int t = threadIdx.x;
#pragma unroll
  for (int k = 0; k < 16; ++k) {
    int i = t*4 + k*1024;
    float4 wv = *(const float4*)(W + i);
    int d = i >> 7, e = i & 127;
    *(float4*)(&Wl[d*132 + e]) = wv;
  }
  {
    int i = t*4;
    int q = i >> 7, e = i & 127;
    *(float4*)(&Ul[q*128 + e]) =
        *(const float4*)(U + ((size_t)(b*Q_ + qc*8 + q))*D_ + e);
  }
  __syncthreads();
  const int d = t & 127, qhalf = t >> 7;
#pragma unroll
  for (int pass = 0; pass < 4; ++pass) {
    const int q = pass*2 + qhalf;
    float acc = 0.f;
#pragma unroll
    for (int e = 0; e < 128; e += 4) {
      float4 wv = *(float4*)(&Wl[d*132 + e]);
      float4 uv = *(float4*)(&Ul[q*128 + e]);
      acc += wv.x*uv.x + wv.y*uv.y + wv.z*uv.z + wv.w*uv.w;
    }
    T[((size_t)(b*Q_ + qc*8 + q))*D_ + d] = acc;
  }
}

// ---------------------------------------------------------------------------
// k_main (MFMA): grid 512 = 32 b * 16 chunks of 256 rows, 512 threads (8 waves)
// Each wave: 2 tiles of 16 rows. S = H*T^T via split-bf16 3-MFMA; P*U single bf16.
// LDS: Thi 16K | Tlo 16K | Ut 16K | P 16K(8 waves x 2K) | tk 1K = 66.5 KB
// -> 2 blocks/CU, 4 waves/SIMD.
// ---------------------------------------------------------------------------
__global__ __launch_bounds__(512, 4) void k_main(
    const float* __restrict__ H, const float* __restrict__ U,
    const float* __restrict__ M, const int* __restrict__ tok,
    const float* __restrict__ T, float* __restrict__ part) {
  __shared__ __align__(16) char smem[16384*4 + 1024];
  char* Thi = smem;                 // bf16 [64 q][128 d], byte = q*256+2d ^ ((q&7)<<4)
  char* Tlo = smem + 16384;
  char* Utl = smem + 32768;         // bf16 [128 d][64 q], byte = d*128+2q ^ ((d&7)<<4)
  char* Pb  = smem + 49152;         // per-wave 2KB: bf16 [16 p][64 q], byte = p*128+2q ^ ((p&7)<<4)
  int* tkl  = (int*)(smem + 65536); // 256 ints

  const int bid = blockIdx.x;
  const int b = bid >> 4, chunk = bid & 15;
  const int t = threadIdx.x, wv = t >> 6, l = t & 63;
  const int r15 = l & 15, g4 = l >> 4;

  // ---- stage T (hi/lo bf16, swizzled) and U^T (bf16, swizzled) ----
  const float* Tb = T + (size_t)b*Q_*D_;
  const float* Ub = U + (size_t)b*Q_*D_;
#pragma unroll
  for (int k = 0; k < 4; ++k) {
    int i = t*4 + k*2048;                 // 8192 floats
    int q = i >> 7, d = i & 127;
    float4 tv = *(const float4*)(Tb + i);
    unsigned int b0 = asu(tv.x), b1 = asu(tv.y), b2 = asu(tv.z), b3 = asu(tv.w);
    unsigned int hi0 = (b1 & 0xFFFF0000u) | (b0 >> 16);
    unsigned int hi1 = (b3 & 0xFFFF0000u) | (b2 >> 16);
    float l0 = tv.x - asf(b0 & 0xFFFF0000u);
    float l1 = tv.y - asf(b1 & 0xFFFF0000u);
    float l2 = tv.z - asf(b2 & 0xFFFF0000u);
    float l3 = tv.w - asf(b3 & 0xFFFF0000u);
    unsigned int lo0 = (asu(l1) & 0xFFFF0000u) | (asu(l0) >> 16);
    unsigned int lo1 = (asu(l3) & 0xFFFF0000u) | (asu(l2) >> 16);
    int ta = (q*256 + 2*d) ^ ((q & 7) << 4);
    *(uint2*)(Thi + ta) = make_uint2(hi0, hi1);
    *(uint2*)(Tlo + ta) = make_uint2(lo0, lo1);
    float4 uv = *(const float4*)(Ub + i);
    float uvv[4] = {uv.x, uv.y, uv.z, uv.w};
#pragma unroll
    for (int j = 0; j < 4; ++j) {
      int dd = d + j;
      int ua = (dd*128 + 2*q) ^ ((dd & 7) << 4);
      *(unsigned short*)(Utl + ua) = (unsigned short)(asu(uvv[j]) >> 16);
    }
  }
  if (t < 256) tkl[t] = tok[b*P_ + chunk*CHUNK_ROWS + t];
  __syncthreads();

  const int rowB = b*P_ + chunk*CHUNK_ROWS;   // absolute row base of block
  char* Pw = Pb + wv*2048;

  float Lmax = -3.0e38f, ssum = 0.f;
  float v[8], mxH[8], mnH[8], mxC[8], mxHC[8];
#pragma unroll
  for (int nt = 0; nt < 8; ++nt) {
    v[nt] = 0.f; mxH[nt] = -3.0e38f; mnH[nt] = 3.0e38f;
    mxC[nt] = -3.0e38f; mxHC[nt] = -3.0e38f;
  }
  float mxM0 = -3.0e38f, mxM1 = -3.0e38f;

#pragma unroll 1
  for (int g = 0; g < 2; ++g) {
    const int lrow0 = g*128 + wv*16;          // block-local tile base row

    // ---- M pool: d-ownership (d = 2l, 2l+1), perfectly coalesced rows ----
    {
      const float* Mrow = M + (size_t)(rowB + lrow0)*D_ + 2*l;
#pragma unroll
      for (int r = 0; r < 16; ++r) {
        float2 mv = *(const float2*)(Mrow + (size_t)r*D_);
        float bm = (tkl[lrow0 + r] != 0) ? 0.f : -1.0e38f;
        mxM0 = fmaxf(mxM0, mv.x + bm);
        mxM1 = fmaxf(mxM1, mv.y + bm);
      }
    }

    // ---- S = H*T^T, split-bf16, 4 q-tiles x 4 k-steps x 3 MFMA ----
    f32x4 sacc[4];
#pragma unroll
    for (int qt = 0; qt < 4; ++qt) sacc[qt] = (f32x4){0.f, 0.f, 0.f, 0.f};
    const float* Arow = H + (size_t)(rowB + lrow0 + r15)*D_;
#pragma unroll
    for (int ks = 0; ks < 4; ++ks) {
      const float* ap = Arow + ks*32 + g4*8;
      float4 fa = *(const float4*)(ap);
      float4 fb = *(const float4*)(ap + 4);
      union { bf16x8 v; unsigned int u[4]; } Ah, Al;
      {
        unsigned int a0 = asu(fa.x), a1 = asu(fa.y), a2 = asu(fa.z), a3 = asu(fa.w);
        unsigned int c0 = asu(fb.x), c1 = asu(fb.y), c2 = asu(fb.z), c3 = asu(fb.w);
        Ah.u[0] = (a1 & 0xFFFF0000u) | (a0 >> 16);
        Ah.u[1] = (a3 & 0xFFFF0000u) | (a2 >> 16);
        Ah.u[2] = (c1 & 0xFFFF0000u) | (c0 >> 16);
        Ah.u[3] = (c3 & 0xFFFF0000u) | (c2 >> 16);
        float p0 = fa.x - asf(a0 & 0xFFFF0000u);
        float p1 = fa.y - asf(a1 & 0xFFFF0000u);
        float p2 = fa.z - asf(a2 & 0xFFFF0000u);
        float p3 = fa.w - asf(a3 & 0xFFFF0000u);
        float p4 = fb.x - asf(c0 & 0xFFFF0000u);
        float p5 = fb.y - asf(c1 & 0xFFFF0000u);
        float p6 = fb.z - asf(c2 & 0xFFFF0000u);
        float p7 = fb.w - asf(c3 & 0xFFFF0000u);
        Al.u[0] = (asu(p1) & 0xFFFF0000u) | (asu(p0) >> 16);
        Al.u[1] = (asu(p3) & 0xFFFF0000u) | (asu(p2) >> 16);
        Al.u[2] = (asu(p5) & 0xFFFF0000u) | (asu(p4) >> 16);
        Al.u[3] = (asu(p7) & 0xFFFF0000u) | (asu(p6) >> 16);
      }
#pragma unroll
      for (int qt = 0; qt < 4; ++qt) {
        int q = qt*16 + r15;
        int off = (q*256 + ks*64 + g4*16) ^ ((q & 7) << 4);
        bf16x8 bh = *(bf16x8*)(Thi + off);
        bf16x8 bl = *(bf16x8*)(Tlo + off);
        sacc[qt] = __builtin_amdgcn_mfma_f32_16x16x32_bf16(Al.v, bh, sacc[qt], 0, 0, 0);
        sacc[qt] = __builtin_amdgcn_mfma_f32_16x16x32_bf16(Ah.v, bl, sacc[qt], 0, 0, 0);
        sacc[qt] = __builtin_amdgcn_mfma_f32_16x16x32_bf16(Ah.v, bh, sacc[qt], 0, 0, 0);
      }
    }

    // ---- row max over q (per lane: 4 rows j), cross-lane over l&15 ----
    float m[4];
#pragma unroll
    for (int j = 0; j < 4; ++j)
      m[j] = fmaxf(fmaxf(sacc[0][j], sacc[1][j]), fmaxf(sacc[2][j], sacc[3][j]));
#pragma unroll
    for (int off = 1; off <= 8; off <<= 1)
#pragma unroll
      for (int j = 0; j < 4; ++j) m[j] = fmaxf(m[j], __shfl_xor(m[j], off));

    // ---- P = exp(S - m) -> bf16 LDS (A-frag layout), Z per row ----
    float Zp[4] = {0.f, 0.f, 0.f, 0.f};
#pragma unroll
    for (int qt = 0; qt < 4; ++qt)
#pragma unroll
      for (int j = 0; j < 4; ++j) {
        float e = __expf(sacc[qt][j] - m[j]);
        Zp[j] += e;
        int p = g4*4 + j, q = qt*16 + r15;
        int off = (p*128 + 2*q) ^ ((p & 7) << 4);
        *(unsigned short*)(Pw + off) = (unsigned short)(asu(e) >> 16);
      }
#pragma unroll
    for (int off = 1; off <= 8; off <<= 1)
#pragma unroll
      for (int j = 0; j < 4; ++j) Zp[j] += __shfl_xor(Zp[j], off);
    float rz[4];
#pragma unroll
    for (int j = 0; j < 4; ++j) rz[j] = __builtin_amdgcn_rcpf(Zp[j]);

    // ---- PV: c2q_unnorm = P * U  (8 n-tiles x 2 k-steps) ----
    f32x4 pv[8];
#pragma unroll
    for (int nt = 0; nt < 8; ++nt) pv[nt] = (f32x4){0.f, 0.f, 0.f, 0.f};
#pragma unroll
    for (int ks2 = 0; ks2 < 2; ++ks2) {
      int qoff = ks2*64 + g4*16;   // bytes
      bf16x8 apv = *(bf16x8*)(Pw + ((r15*128 + qoff) ^ ((r15 & 7) << 4)));
#pragma unroll
      for (int nt = 0; nt < 8; ++nt) {
        int dd = nt*16 + r15;
        bf16x8 bu = *(bf16x8*)(Utl + ((dd*128 + qoff) ^ ((dd & 7) << 4)));
        pv[nt] = __builtin_amdgcn_mfma_f32_16x16x32_bf16(apv, bu, pv[nt], 0, 0, 0);
      }
    }

    // ---- per-j: pools (C-layout) + online q2c ----
    const float* HrowC = H + (size_t)(rowB + lrow0 + g4*4)*D_ + r15;
#pragma unroll
    for (int j = 0; j < 4; ++j) {
      int tkv = tkl[lrow0 + g4*4 + j];
      float bmax = (tkv != 0) ? 0.f : -1.0e38f;
      float bmin = (tkv != 0) ? 0.f : 1.0e38f;
      float nm = fmaxf(Lmax, m[j]);
      float so = __expf(Lmax - nm);
      float pr = __expf(m[j] - nm);
      Lmax = nm;
      ssum = ssum*so + pr;
#pragma unroll
      for (int nt = 0; nt < 8; ++nt) {
        float hv = HrowC[(size_t)j*D_ + nt*16];
        float c  = pv[nt][j] * rz[j];
        v[nt]    = v[nt]*so + pr*hv;
        mxH[nt]  = fmaxf(mxH[nt],  hv + bmax);
        mnH[nt]  = fminf(mnH[nt],  hv + bmin);
        mxC[nt]  = fmaxf(mxC[nt],  c + bmax);
        mxHC[nt] = fmaxf(mxHC[nt], hv*c + bmax);
      }
    }
  }

  // ---- cross-lane merge over the 4 lane-groups (xor 16, 32) ----
#pragma unroll
  for (int off = 16; off <= 32; off <<= 1) {
    float oL = __shfl_xor(Lmax, off);
    float nm = fmaxf(Lmax, oL);
    float a  = __expf(Lmax - nm);
    float bb = __expf(oL - nm);
#pragma unroll
    for (int nt = 0; nt < 8; ++nt)
      v[nt] = v[nt]*a + __shfl_xor(v[nt], off)*bb;
    ssum = ssum*a + __shfl_xor(ssum, off)*bb;
    Lmax = nm;
  }
#pragma unroll
  for (int off = 16; off <= 32; off <<= 1)
#pragma unroll
    for (int nt = 0; nt < 8; ++nt) {
      mxH[nt]  = fmaxf(mxH[nt],  __shfl_xor(mxH[nt],  off));
      mnH[nt]  = fminf(mnH[nt],  __shfl_xor(mnH[nt],  off));
      mxC[nt]  = fmaxf(mxC[nt],  __shfl_xor(mxC[nt],  off));
      mxHC[nt] = fmaxf(mxHC[nt], __shfl_xor(mxHC[nt], off));
    }

  __syncthreads();                      // T region done -> reuse as combine scratch
  float* comb = (float*)smem;           // 8 waves x 772 floats = 24.7 KB
  float* sc = comb + wv*PART_STRIDE;
  if (l == 0) { sc[0] = Lmax; sc[1] = ssum; }
  if (l < 16) {
#pragma unroll
    for (int nt = 0; nt < 8; ++nt) {
      int dd = nt*16 + l;
      sc[2 + dd]   = v[nt];
      sc[130 + dd] = mxH[nt];
      sc[258 + dd] = mnH[nt];
      sc[386 + dd] = mxC[nt];
      sc[514 + dd] = mxHC[nt];
    }
  }
  sc[642 + 2*l]     = mxM0;
  sc[642 + 2*l + 1] = mxM1;
  __syncthreads();

  if (t < 128) {
    float L = -3.0e38f;
#pragma unroll
    for (int w = 0; w < 8; ++w) L = fmaxf(L, comb[w*PART_STRIDE]);
    float S = 0.f, V = 0.f;
    float mh = -3.0e38f, nh = 3.0e38f, mc = -3.0e38f, mhc = -3.0e38f, mm = -3.0e38f;
#pragma unroll
    for (int w = 0; w < 8; ++w) {
      const float* s0 = comb + w*PART_STRIDE;
      float e = __expf(s0[0] - L);
      S += s0[1]*e;
      V += s0[2 + t]*e;
      mh  = fmaxf(mh,  s0[130 + t]);
      nh  = fminf(nh,  s0[258 + t]);
      mc  = fmaxf(mc,  s0[386 + t]);
      mhc = fmaxf(mhc, s0[514 + t]);
      mm  = fmaxf(mm,  s0[642 + t]);
    }
    float* pp = part + (size_t)bid*PART_STRIDE;
    if (t == 0) { pp[0] = L; pp[1] = S; }
    pp[2 + t]   = V;
    pp[130 + t] = mh;
    pp[258 + t] = nh;
    pp[386 + t] = mc;
    pp[514 + t] = mhc;
    pp[642 + t] = mm;
  }
}

// ---------------------------------------------------------------------------
// k_final: merge 16 chunk-partials per batch, build pooled[640], classifier
// grid 32 (one per batch), 128 threads (t = d)
// ---------------------------------------------------------------------------
__global__ __launch_bounds__(128) void k_final(const float* __restrict__ part,
                                               const float* __restrict__ Wc,
                                               float* __restrict__ out) {
  __shared__ float pooled[640];
  __shared__ float r0s[2], r1s[2];
  const int b = blockIdx.x, t = threadIdx.x;
  const float* pb = part + (size_t)b*NCHUNK*PART_STRIDE;
  float L = -3.0e38f;
#pragma unroll
  for (int c = 0; c < NCHUNK; ++c) L = fmaxf(L, pb[c*PART_STRIDE]);
  float S = 0.f, V = 0.f;
  float mh = -3.0e38f, nh = 3.0e38f, mc = -3.0e38f, mhc = -3.0e38f, mm = -3.0e38f;
#pragma unroll
  for (int c = 0; c < NCHUNK; ++c) {
    const float* p = pb + c*PART_STRIDE;
    float e = __expf(p[0] - L);
    S += p[1]*e;
    V += p[2 + t]*e;
    mh  = fmaxf(mh,  p[130 + t]);
    nh  = fminf(nh,  p[258 + t]);
    mc  = fmaxf(mc,  p[386 + t]);
    mhc = fmaxf(mhc, p[514 + t]);
    mm  = fmaxf(mm,  p[642 + t]);
  }
  float q2c = V / S;
  pooled[t]       = mh;
  pooled[128 + t] = mc;
  pooled[256 + t] = mhc;
  pooled[384 + t] = (q2c >= 0.f) ? q2c*mh : q2c*nh;
  pooled[512 + t] = mm;
  __syncthreads();
  float a0 = 0.f, a1 = 0.f;
#pragma unroll
  for (int k = t; k < 640; k += 128) {
    float pv = pooled[k];
    a0 += pv*Wc[k*2 + 0];
    a1 += pv*Wc[k*2 + 1];
  }
#pragma unroll
  for (int off = 32; off; off >>= 1) {
    a0 += __shfl_xor(a0, off);
    a1 += __shfl_xor(a1, off);
  }
  if ((t & 63) == 0) { r0s[t >> 6] = a0; r1s[t >> 6] = a1; }
  __syncthreads();
  if (t == 0) {
    out[b*2 + 0] = r0s[0] + r0s[1];
    out[b*2 + 1] = r1s[0] + r1s[1];
  }
}

// ---------------------------------------------------------------------------
extern "C" void kernel_launch(void* const* d_in, const int* in_sizes, int n_in,
                              void* d_out, int out_size, void* d_ws, size_t ws_size,
                              hipStream_t stream) {
  const float* H   = (const float*)d_in[0];
  const float* U   = (const float*)d_in[1];
  const float* M   = (const float*)d_in[2];
  const int*   tok = (const int*)d_in[3];
  const float* Wa  = (const float*)d_in[4];
  const float* Wc  = (const float*)d_in[5];
  float* out = (float*)d_out;
  float* wsf = (float*)d_ws;
  float* T    = wsf;
  float* part = wsf + T_SIZE;

  hipLaunchKernelGGL(k_T,     dim3(256),        dim3(256), 0, stream, U, Wa, T);
  hipLaunchKernelGGL(k_main,  dim3(B_*NCHUNK),  dim3(512), 0, stream, H, U, M, tok, T, part);
  hipLaunchKernelGGL(k_final, dim3(B_),         dim3(128), 0, stream, part, Wc, out);
}

// Round 4
// 58.266 us; speedup vs baseline: 23.3507x; 1.8157x over previous
//
#include <hip/hip_runtime.h>

#define B_ 32
#define P_ 4096
#define Q_ 64
#define D_ 128

#define T_SIZE (B_*Q_*D_)       // 262144 floats (fp32 T workspace)
#define PART_STRIDE 772         // [L, S, v:128, mxH:128, mnH:128, mxC:128, mxHC:128, mxM:128]
#define NCHUNK 32
#define CHUNK_ROWS 128

typedef __attribute__((ext_vector_type(8))) short bf16x8;
typedef __attribute__((ext_vector_type(4))) float f32x4;

__device__ __forceinline__ unsigned int asu(float x) { return __float_as_uint(x); }
__device__ __forceinline__ float asf(unsigned int x) { return __uint_as_float(x); }

// ---------------------------------------------------------------------------
// k_T: T[b,q,d] = sum_e W[d,e] * U[b,q,e]   (fp32)
// grid 256 = 32 b * 8 q-chunks, 256 threads
// ---------------------------------------------------------------------------
__global__ __launch_bounds__(256) void k_T(const float* __restrict__ U,
                                           const float* __restrict__ W,
                                           float* __restrict__ T) {
  __shared__ float Wl[128*132];
  __shared__ float Ul[8*128];
  const int b = blockIdx.x >> 3, qc = blockIdx.x & 7;
  const int t = threadIdx.x;
#pragma unroll
  for (int k = 0; k < 16; ++k) {
    int i = t*4 + k*1024;
    float4 wv = *(const float4*)(W + i);
    int d = i >> 7, e = i & 127;
    *(float4*)(&Wl[d*132 + e]) = wv;
  }
  {
    int i = t*4;
    int q = i >> 7, e = i & 127;
    *(float4*)(&Ul[q*128 + e]) =
        *(const float4*)(U + ((size_t)(b*Q_ + qc*8 + q))*D_ + e);
  }
  __syncthreads();
  const int d = t & 127, qhalf = t >> 7;
#pragma unroll
  for (int pass = 0; pass < 4; ++pass) {
    const int q = pass*2 + qhalf;
    float acc = 0.f;
#pragma unroll
    for (int e = 0; e < 128; e += 4) {
      float4 wv = *(float4*)(&Wl[d*132 + e]);
      float4 uv = *(float4*)(&Ul[q*128 + e]);
      acc += wv.x*uv.x + wv.y*uv.y + wv.z*uv.z + wv.w*uv.w;
    }
    T[((size_t)(b*Q_ + qc*8 + q))*D_ + d] = acc;
  }
}

// ---------------------------------------------------------------------------
// k_main v2: grid 1024 = 32 b * 32 chunks of 128 rows, 512 threads (8 waves).
// Phase 1: wave wv computes S/softmax for row-tile wv -> P(bf16), m, 1/Z in LDS.
// Phase 2: wave wv owns d-slice [wv*16, wv*16+16): sweeps all 8 P-tiles with
//          2 MFMAs each; pools + q2c per lane for a SINGLE d (no spill).
// LDS: Thi 16K | Tlo 16K | Ut 16K | P 16K | mrow/rzrow/tok 1.5K = 65.5 KB
// ---------------------------------------------------------------------------
__global__ __launch_bounds__(512, 4) void k_main(
    const float* __restrict__ H, const float* __restrict__ U,
    const float* __restrict__ M, const int* __restrict__ tok,
    const float* __restrict__ T, float* __restrict__ part) {
  __shared__ __align__(16) char smem[16384*4 + 1536];
  char* Thi = smem;                  // bf16 [64 q][128 d], byte = q*256+2d ^ ((q&7)<<4)
  char* Tlo = smem + 16384;
  char* Utl = smem + 32768;          // bf16 [128 d][64 q], byte = d*128+2q ^ ((d&7)<<4)
  char* Pl  = smem + 49152;          // bf16 [128 p][64 q], byte = p*128+2q ^ ((p&7)<<4)
  float* mrow  = (float*)(smem + 65536);   // 128 row maxes
  float* rzrow = (float*)(smem + 66048);   // 128 reciprocal Z
  int*   tkl   = (int*)(smem + 66560);     // 128 tokens

  const int bid = blockIdx.x;
  const int b = bid >> 5, chunk = bid & 31;
  const int t = threadIdx.x, wv = t >> 6, l = t & 63;
  const int r15 = l & 15, g4 = l >> 4;

  // ---- stage T (hi/lo bf16, swizzled) and U^T (bf16, swizzled) ----
  const float* Tb = T + (size_t)b*Q_*D_;
  const float* Ub = U + (size_t)b*Q_*D_;
#pragma unroll
  for (int k = 0; k < 4; ++k) {
    int i = t*4 + k*2048;                 // 8192 floats
    int q = i >> 7, d = i & 127;
    float4 tv = *(const float4*)(Tb + i);
    unsigned int b0 = asu(tv.x), b1 = asu(tv.y), b2 = asu(tv.z), b3 = asu(tv.w);
    unsigned int hi0 = (b1 & 0xFFFF0000u) | (b0 >> 16);
    unsigned int hi1 = (b3 & 0xFFFF0000u) | (b2 >> 16);
    float l0 = tv.x - asf(b0 & 0xFFFF0000u);
    float l1 = tv.y - asf(b1 & 0xFFFF0000u);
    float l2 = tv.z - asf(b2 & 0xFFFF0000u);
    float l3 = tv.w - asf(b3 & 0xFFFF0000u);
    unsigned int lo0 = (asu(l1) & 0xFFFF0000u) | (asu(l0) >> 16);
    unsigned int lo1 = (asu(l3) & 0xFFFF0000u) | (asu(l2) >> 16);
    int ta = (q*256 + 2*d) ^ ((q & 7) << 4);
    *(uint2*)(Thi + ta) = make_uint2(hi0, hi1);
    *(uint2*)(Tlo + ta) = make_uint2(lo0, lo1);
    float4 uv = *(const float4*)(Ub + i);
    float uvv[4] = {uv.x, uv.y, uv.z, uv.w};
#pragma unroll
    for (int j = 0; j < 4; ++j) {
      int dd = d + j;
      int ua = (dd*128 + 2*q) ^ ((dd & 7) << 4);
      *(unsigned short*)(Utl + ua) = (unsigned short)(asu(uvv[j]) >> 16);
    }
  }
  if (t < 128) tkl[t] = tok[b*P_ + chunk*CHUNK_ROWS + t];
  __syncthreads();

  const int rowB = b*P_ + chunk*CHUNK_ROWS;

  // ================= phase 1: S + softmax for my 16-row tile =================
  {
    const int lrow0 = wv*16;
    f32x4 sacc[4];
#pragma unroll
    for (int qt = 0; qt < 4; ++qt) sacc[qt] = (f32x4){0.f, 0.f, 0.f, 0.f};
    const float* Arow = H + (size_t)(rowB + lrow0 + r15)*D_;
#pragma unroll
    for (int ks = 0; ks < 4; ++ks) {
      const float* ap = Arow + ks*32 + g4*8;
      float4 fa = *(const float4*)(ap);
      float4 fb = *(const float4*)(ap + 4);
      union { bf16x8 v; unsigned int u[4]; } Ah, Al;
      {
        unsigned int a0 = asu(fa.x), a1 = asu(fa.y), a2 = asu(fa.z), a3 = asu(fa.w);
        unsigned int c0 = asu(fb.x), c1 = asu(fb.y), c2 = asu(fb.z), c3 = asu(fb.w);
        Ah.u[0] = (a1 & 0xFFFF0000u) | (a0 >> 16);
        Ah.u[1] = (a3 & 0xFFFF0000u) | (a2 >> 16);
        Ah.u[2] = (c1 & 0xFFFF0000u) | (c0 >> 16);
        Ah.u[3] = (c3 & 0xFFFF0000u) | (c2 >> 16);
        float p0 = fa.x - asf(a0 & 0xFFFF0000u);
        float p1 = fa.y - asf(a1 & 0xFFFF0000u);
        float p2 = fa.z - asf(a2 & 0xFFFF0000u);
        float p3 = fa.w - asf(a3 & 0xFFFF0000u);
        float p4 = fb.x - asf(c0 & 0xFFFF0000u);
        float p5 = fb.y - asf(c1 & 0xFFFF0000u);
        float p6 = fb.z - asf(c2 & 0xFFFF0000u);
        float p7 = fb.w - asf(c3 & 0xFFFF0000u);
        Al.u[0] = (asu(p1) & 0xFFFF0000u) | (asu(p0) >> 16);
        Al.u[1] = (asu(p3) & 0xFFFF0000u) | (asu(p2) >> 16);
        Al.u[2] = (asu(p5) & 0xFFFF0000u) | (asu(p4) >> 16);
        Al.u[3] = (asu(p7) & 0xFFFF0000u) | (asu(p6) >> 16);
      }
#pragma unroll
      for (int qt = 0; qt < 4; ++qt) {
        int q = qt*16 + r15;
        int off = (q*256 + ks*64 + g4*16) ^ ((q & 7) << 4);
        bf16x8 bh = *(bf16x8*)(Thi + off);
        bf16x8 bl = *(bf16x8*)(Tlo + off);
        sacc[qt] = __builtin_amdgcn_mfma_f32_16x16x32_bf16(Al.v, bh, sacc[qt], 0, 0, 0);
        sacc[qt] = __builtin_amdgcn_mfma_f32_16x16x32_bf16(Ah.v, bl, sacc[qt], 0, 0, 0);
        sacc[qt] = __builtin_amdgcn_mfma_f32_16x16x32_bf16(Ah.v, bh, sacc[qt], 0, 0, 0);
      }
    }
    // row max over q (C-layout: lane holds rows g4*4+j, col qt*16+r15)
    float m[4];
#pragma unroll
    for (int j = 0; j < 4; ++j)
      m[j] = fmaxf(fmaxf(sacc[0][j], sacc[1][j]), fmaxf(sacc[2][j], sacc[3][j]));
#pragma unroll
    for (int off = 1; off <= 8; off <<= 1)
#pragma unroll
      for (int j = 0; j < 4; ++j) m[j] = fmaxf(m[j], __shfl_xor(m[j], off));
    // P = exp(S - m) -> bf16 LDS, Z per row
    float Zp[4] = {0.f, 0.f, 0.f, 0.f};
#pragma unroll
    for (int qt = 0; qt < 4; ++qt)
#pragma unroll
      for (int j = 0; j < 4; ++j) {
        float e = __expf(sacc[qt][j] - m[j]);
        Zp[j] += e;
        int p = lrow0 + g4*4 + j, q = qt*16 + r15;
        int off = (p*128 + 2*q) ^ ((p & 7) << 4);
        *(unsigned short*)(Pl + off) = (unsigned short)(asu(e) >> 16);
      }
#pragma unroll
    for (int off = 1; off <= 8; off <<= 1)
#pragma unroll
      for (int j = 0; j < 4; ++j) Zp[j] += __shfl_xor(Zp[j], off);
    if (r15 == 0) {
#pragma unroll
      for (int j = 0; j < 4; ++j) {
        mrow[lrow0 + g4*4 + j]  = m[j];
        rzrow[lrow0 + g4*4 + j] = __builtin_amdgcn_rcpf(Zp[j]);
      }
    }
  }
  __syncthreads();

  // ================= phase 2: my d-slice over all 8 tiles =================
  // block softmax stats (wave-uniform, redundant per wave)
  float m0 = mrow[l], m1 = mrow[l + 64];
  float Lm = fmaxf(m0, m1);
#pragma unroll
  for (int off = 1; off <= 32; off <<= 1) Lm = fmaxf(Lm, __shfl_xor(Lm, off));
  float ssum = __expf(m0 - Lm) + __expf(m1 - Lm);
#pragma unroll
  for (int off = 1; off <= 32; off <<= 1) ssum += __shfl_xor(ssum, off);

  const int dd = wv*16 + r15;
  // loop-invariant U^T B-fragments for my d
  bf16x8 bu0 = *(bf16x8*)(Utl + ((dd*128 +  0 + g4*16) ^ ((dd & 7) << 4)));
  bf16x8 bu1 = *(bf16x8*)(Utl + ((dd*128 + 64 + g4*16) ^ ((dd & 7) << 4)));

  float v = 0.f, xH = -3.0e38f, nH = 3.0e38f;
  float xC = -3.0e38f, xHC = -3.0e38f, xM = -3.0e38f;
#pragma unroll
  for (int rti = 0; rti < 8; ++rti) {
    const int rt = (rti + wv) & 7;          // stagger waves across tiles
    f32x4 pv = (f32x4){0.f, 0.f, 0.f, 0.f};
    {
      int pr0 = rt*16 + r15;
      bf16x8 a0 = *(bf16x8*)(Pl + ((pr0*128 +  0 + g4*16) ^ ((r15 & 7) << 4)));
      bf16x8 a1 = *(bf16x8*)(Pl + ((pr0*128 + 64 + g4*16) ^ ((r15 & 7) << 4)));
      pv = __builtin_amdgcn_mfma_f32_16x16x32_bf16(a0, bu0, pv, 0, 0, 0);
      pv = __builtin_amdgcn_mfma_f32_16x16x32_bf16(a1, bu1, pv, 0, 0, 0);
    }
    const float* Hrow = H + (size_t)(rowB + rt*16 + g4*4)*D_ + dd;
    const float* Mrow = M + (size_t)(rowB + rt*16 + g4*4)*D_ + dd;
#pragma unroll
    for (int j = 0; j < 4; ++j) {
      const int row = rt*16 + g4*4 + j;
      const int tkv = tkl[row];
      const float bmax = tkv ? 0.f : -1.0e38f;
      const float bmin = tkv ? 0.f : 1.0e38f;
      float pr = __expf(mrow[row] - Lm);
      float h  = Hrow[(size_t)j*D_];
      float mv = Mrow[(size_t)j*D_];
      float c  = pv[j] * rzrow[row];
      v   += pr*h;
      xH   = fmaxf(xH,  h + bmax);
      nH   = fminf(nH,  h + bmin);
      xC   = fmaxf(xC,  c + bmax);
      xHC  = fmaxf(xHC, h*c + bmax);
      xM   = fmaxf(xM,  mv + bmax);
    }
  }
  // merge the 4 row-groups (g4) holding the same d
#pragma unroll
  for (int off = 16; off <= 32; off <<= 1) {
    v   += __shfl_xor(v, off);
    xH   = fmaxf(xH,  __shfl_xor(xH,  off));
    nH   = fminf(nH,  __shfl_xor(nH,  off));
    xC   = fmaxf(xC,  __shfl_xor(xC,  off));
    xHC  = fmaxf(xHC, __shfl_xor(xHC, off));
    xM   = fmaxf(xM,  __shfl_xor(xM,  off));
  }
  float* pp = part + (size_t)bid*PART_STRIDE;
  if (t == 0) { pp[0] = Lm; pp[1] = ssum; }
  if (g4 == 0) {
    pp[2 + dd]   = v;
    pp[130 + dd] = xH;
    pp[258 + dd] = nH;
    pp[386 + dd] = xC;
    pp[514 + dd] = xHC;
    pp[642 + dd] = xM;
  }
}

// ---------------------------------------------------------------------------
// k_final: merge 32 chunk-partials per batch, build pooled[640], classifier
// grid 32 (one per batch), 128 threads (t = d)
// ---------------------------------------------------------------------------
__global__ __launch_bounds__(128) void k_final(const float* __restrict__ part,
                                               const float* __restrict__ Wc,
                                               float* __restrict__ out) {
  __shared__ float pooled[640];
  __shared__ float r0s[2], r1s[2];
  const int b = blockIdx.x, t = threadIdx.x;
  const float* pb = part + (size_t)b*NCHUNK*PART_STRIDE;
  float L = -3.0e38f;
#pragma unroll
  for (int c = 0; c < NCHUNK; ++c) L = fmaxf(L, pb[c*PART_STRIDE]);
  float S = 0.f, V = 0.f;
  float mh = -3.0e38f, nh = 3.0e38f, mc = -3.0e38f, mhc = -3.0e38f, mm = -3.0e38f;
#pragma unroll
  for (int c = 0; c < NCHUNK; ++c) {
    const float* p = pb + c*PART_STRIDE;
    float e = __expf(p[0] - L);
    S += p[1]*e;
    V += p[2 + t]*e;
    mh  = fmaxf(mh,  p[130 + t]);
    nh  = fminf(nh,  p[258 + t]);
    mc  = fmaxf(mc,  p[386 + t]);
    mhc = fmaxf(mhc, p[514 + t]);
    mm  = fmaxf(mm,  p[642 + t]);
  }
  float q2c = V / S;
  pooled[t]       = mh;
  pooled[128 + t] = mc;
  pooled[256 + t] = mhc;
  pooled[384 + t] = (q2c >= 0.f) ? q2c*mh : q2c*nh;
  pooled[512 + t] = mm;
  __syncthreads();
  float a0 = 0.f, a1 = 0.f;
#pragma unroll
  for (int k = t; k < 640; k += 128) {
    float pv = pooled[k];
    a0 += pv*Wc[k*2 + 0];
    a1 += pv*Wc[k*2 + 1];
  }
#pragma unroll
  for (int off = 32; off; off >>= 1) {
    a0 += __shfl_xor(a0, off);
    a1 += __shfl_xor(a1, off);
  }
  if ((t & 63) == 0) { r0s[t >> 6] = a0; r1s[t >> 6] = a1; }
  __syncthreads();
  if (t == 0) {
    out[b*2 + 0] = r0s[0] + r0s[1];
    out[b*2 + 1] = r1s[0] + r1s[1];
  }
}

// ---------------------------------------------------------------------------
extern "C" void kernel_launch(void* const* d_in, const int* in_sizes, int n_in,
                              void* d_out, int out_size, void* d_ws, size_t ws_size,
                              hipStream_t stream) {
  const float* H   = (const float*)d_in[0];
  const float* U   = (const float*)d_in[1];
  const float* M   = (const float*)d_in[2];
  const int*   tok = (const int*)d_in[3];
  const float* Wa  = (const float*)d_in[4];
  const float* Wc  = (const float*)d_in[5];
  float* out = (float*)d_out;
  float* wsf = (float*)d_ws;
  float* T    = wsf;
  float* part = wsf + T_SIZE;

  hipLaunchKernelGGL(k_T,     dim3(256),        dim3(256), 0, stream, U, Wa, T);
  hipLaunchKernelGGL(k_main,  dim3(B_*NCHUNK),  dim3(512), 0, stream, H, U, M, tok, T, part);
  hipLaunchKernelGGL(k_final, dim3(B_),         dim3(128), 0, stream, part, Wc, out);
}